// Round 12
// baseline (508.477 us; speedup 1.0000x reference)
//
#include <hip/hip_runtime.h>

// Guided filter, Round 9 (fourth submit — three GPUAcquisitionTimeouts on
// this exact source; never measured): wave-autonomous scanline + latency fixes.
// r8 post-mortem: dur 142us, VALUBusy 31%, VGPR=40, occupancy 51% ->
// latency-bound (guarded loads never pipelined) AND grid-limited (20 waves/CU).
// VALU-busy time was only ~44us (vs r6's 69us) -> structure is worth fixing:
// - UNCONDITIONAL clamped loads (clamp gy,c0 into bounds; cndmask values
//   after) so the compiler can issue loads early.
// - Depth-3 prefetch ring fI/fP[3], slot r%3 == h-ring modulus -> one x3
//   unroll, all static indices; row r+3's load issues ~600cy before use.
// - RG_H 64->32: 36 iters/wave (12x3, no tail), grid (5,4,128): 10240 waves
//   = 40/CU demand vs 32 cap (was 20/CU).
// - launch_bounds(256,8): VGPR est ~56 <= 64 -> 8 waves/SIMD.

constexpr int W = 512, H = 512;
constexpr int OUTW = 120;     // output cols per band (raw span 128)
constexpr int RG_H = 32;      // output rows per wave
constexpr float EPS = 0.01f;

#define GF_AB_COL(cx, wI, wP, wII, wIP, aa, bb)                               \
    {                                                                         \
        const float inv = __builtin_amdgcn_rcpf((cx) * cyA);                  \
        const float mI = (wI) * inv, mP = (wP) * inv;                         \
        const float varI = fmaf(-mI, mI, (wII) * inv);                        \
        const float cov  = fmaf(-mI, mP, (wIP) * inv);                        \
        aa = cov * __builtin_amdgcn_rcpf(varI + EPS);                         \
        bb = fmaf(-aa, mI, mP);                                               \
    }

#define GF_STEP(r, S, SP1)                                                    \
  {                                                                           \
    const int gy = oy0 - 2 + (r);                                             \
    const bool ok = xok & ((unsigned)gy < (unsigned)H);                       \
    const float ix = ok ? fI[S].x : 0.f;                                      \
    const float iy = ok ? fI[S].y : 0.f;                                      \
    const float px = ok ? fP[S].x : 0.f;                                      \
    const float py = ok ? fP[S].y : 0.f;                                      \
    {   /* refill slot S with row r+3: clamped, UNCONDITIONAL */              \
        const int gn = gy + 3;                                                \
        const int gc = gn < 0 ? 0 : (gn > H - 1 ? H - 1 : gn);                \
        fI[S] = *(const float2*)(Ic0 + (size_t)gc * W);                       \
        fP[S] = *(const float2*)(Pc0 + (size_t)gc * W);                       \
    }                                                                         \
    const float iLy = __shfl(iy, lm1);                                        \
    const float pLy = __shfl(py, lm1);                                        \
    const float iRx = __shfl(ix, lp1);                                        \
    const float pRx = __shfl(px, lp1);                                        \
    const float cI = ix + iy, cP = px + py;                                   \
    hI0[S] = cI + iLy;  hI1[S] = cI + iRx;                                    \
    hP0[S] = cP + pLy;  hP1[S] = cP + pRx;                                    \
    const float cII = fmaf(ix, ix, iy * iy);                                  \
    const float cIP = fmaf(ix, px, iy * py);                                  \
    hII0[S] = fmaf(iLy, iLy, cII);  hII1[S] = fmaf(iRx, iRx, cII);            \
    hIP0[S] = fmaf(iLy, pLy, cIP);  hIP1[S] = fmaf(iRx, pRx, cIP);            \
    iC0[S] = ix; iC1[S] = iy;                                                 \
    const int ay = gy - 1;                                                    \
    const float cyA = 3.f - (float)(ay == 0) - (float)(ay == H - 1);          \
    const bool abok = xok & ((unsigned)ay < (unsigned)H);                     \
    float a0, b0, a1, b1;                                                     \
    GF_AB_COL(cx0, hI0[0] + hI0[1] + hI0[2], hP0[0] + hP0[1] + hP0[2],        \
              hII0[0] + hII0[1] + hII0[2], hIP0[0] + hIP0[1] + hIP0[2],       \
              a0, b0)                                                         \
    GF_AB_COL(cx1, hI1[0] + hI1[1] + hI1[2], hP1[0] + hP1[1] + hP1[2],        \
              hII1[0] + hII1[1] + hII1[2], hIP1[0] + hIP1[1] + hIP1[2],       \
              a1, b1)                                                         \
    a0 = abok ? a0 : 0.f;  b0 = abok ? b0 : 0.f;                              \
    a1 = abok ? a1 : 0.f;  b1 = abok ? b1 : 0.f;                              \
    const float aLy = __shfl(a1, lm1);                                        \
    const float bLy = __shfl(b1, lm1);                                        \
    const float aRx = __shfl(a0, lp1);                                        \
    const float bRx = __shfl(b0, lp1);                                        \
    const float cA = a0 + a1, cB = b0 + b1;                                   \
    hA0[S] = cA + aLy;  hA1[S] = cA + aRx;                                    \
    hB0[S] = cB + bLy;  hB1[S] = cB + bRx;                                    \
    if ((r) >= 4) {                                                           \
        const int oy = gy - 2;                                                \
        const float cyO = 3.f - (float)(oy == 0) - (float)(oy == H - 1);      \
        const float q0 = __builtin_amdgcn_rcpf(cx0 * cyO);                    \
        const float q1 = __builtin_amdgcn_rcpf(cx1 * cyO);                    \
        const float sA0 = hA0[0] + hA0[1] + hA0[2];                           \
        const float sB0 = hB0[0] + hB0[1] + hB0[2];                           \
        const float sA1 = hA1[0] + hA1[1] + hA1[2];                           \
        const float sB1 = hB1[0] + hB1[1] + hB1[2];                           \
        const float o0 = fmaf(sA0 * q0, iC0[SP1], sB0 * q0);                  \
        const float o1 = fmaf(sA1 * q1, iC1[SP1], sB1 * q1);                  \
        if (stok) *(float2*)(Ob + oy * W + c0) = make_float2(o0, o1);         \
    }                                                                         \
  }

__global__ __launch_bounds__(256, 8) void guide_filter_kernel(
    const float* __restrict__ I, const float* __restrict__ P,
    float* __restrict__ O)
{
    const int lane = threadIdx.x & 63;
    const int wid  = threadIdx.x >> 6;
    const int band = blockIdx.x;                  // 0..4
    const int rg   = blockIdx.y * 4 + wid;        // 0..15
    const size_t img_off = (size_t)blockIdx.z * (size_t)(W * H);
    const float* Ib = I + img_off;
    const float* Pb = P + img_off;
    float*       Ob = O + img_off;

    const int c0 = band * OUTW - 2 + 2 * lane;    // even -> float2 aligned
    const int c1 = c0 + 1;
    const int c0c = c0 < 0 ? 0 : (c0 > W - 2 ? W - 2 : c0);  // clamped, even
    const bool xok  = (unsigned)c0 < (unsigned)W;
    const bool stok = xok & (lane >= 1) & (lane <= 60);
    const float cx0 = 3.f - (float)(c0 == 0);     // c0 even, never W-1
    const float cx1 = 3.f - (float)(c1 == W - 1); // c1 odd, never 0
    const int oy0 = rg * RG_H;
    const int lm1 = lane - 1, lp1 = lane + 1;
    const float* Ic0 = Ib + c0c;
    const float* Pc0 = Pb + c0c;

    float hI0[3], hI1[3], hP0[3], hP1[3], hII0[3], hII1[3], hIP0[3], hIP1[3];
    float hA0[3], hA1[3], hB0[3], hB1[3], iC0[3], iC1[3];
    #pragma unroll
    for (int s = 0; s < 3; ++s) {
        hI0[s]=hI1[s]=hP0[s]=hP1[s]=hII0[s]=hII1[s]=hIP0[s]=hIP1[s]=0.f;
        hA0[s]=hA1[s]=hB0[s]=hB1[s]=iC0[s]=iC1[s]=0.f;
    }

    // Prologue: preload rows r=0,1,2 into prefetch slots (clamped).
    float2 fI[3], fP[3];
    #pragma unroll
    for (int s = 0; s < 3; ++s) {
        const int gn = oy0 - 2 + s;
        const int gc = gn < 0 ? 0 : (gn > H - 1 ? H - 1 : gn);
        fI[s] = *(const float2*)(Ic0 + (size_t)gc * W);
        fP[s] = *(const float2*)(Pc0 + (size_t)gc * W);
    }

    // 36 raw-row iterations = 12 groups of 3 (static ring slots, no tail).
    for (int g = 0; g < 12; ++g) {
        const int r = 3 * g;
        GF_STEP(r,     0, 1)
        GF_STEP(r + 1, 1, 2)
        GF_STEP(r + 2, 2, 0)
    }
}

extern "C" void kernel_launch(void* const* d_in, const int* in_sizes, int n_in,
                              void* d_out, int out_size, void* d_ws, size_t ws_size,
                              hipStream_t stream) {
    const float* I = (const float*)d_in[0];   // input
    const float* P = (const float*)d_in[1];   // guide
    float*       O = (float*)d_out;
    const int images = in_sizes[0] / (W * H); // B*C = 128
    dim3 grid(5, 4, images);                  // 5 bands x (4x4 waves) row-groups
    guide_filter_kernel<<<grid, dim3(256), 0, stream>>>(I, P, O);
}

// Round 16
// 325.492 us; speedup vs baseline: 1.5622x; 1.5622x over previous
//
#include <hip/hip_runtime.h>

// Guided filter, Round 13 (fourth submit — three GPUAcquisitionTimeouts on
// this exact source; never measured): scanline, spill fix.
// r9 post-mortem: launch_bounds(256,8) => 64-VGPR cap; ring state (~80 regs)
// spilled to scratch: VGPR=32, WRITE_SIZE 131->447MB, FETCH 181->458MB,
// VALUBusy 16%, dur 314us. The prefetch-ring hypothesis was never tested.
// ONE change: launch_bounds(256,4) -> 128-VGPR cap, no spill, 16 waves/CU.
// ILP (6 loads in flight, issued 3 iters ahead) covers latency instead of TLP.
// Decision rule: dur >= 121us (r6 best) kills this arc -> revert to r6.

constexpr int W = 512, H = 512;
constexpr int OUTW = 120;     // output cols per band (raw span 128)
constexpr int RG_H = 32;      // output rows per wave
constexpr float EPS = 0.01f;

#define GF_AB_COL(cx, wI, wP, wII, wIP, aa, bb)                               \
    {                                                                         \
        const float inv = __builtin_amdgcn_rcpf((cx) * cyA);                  \
        const float mI = (wI) * inv, mP = (wP) * inv;                         \
        const float varI = fmaf(-mI, mI, (wII) * inv);                        \
        const float cov  = fmaf(-mI, mP, (wIP) * inv);                        \
        aa = cov * __builtin_amdgcn_rcpf(varI + EPS);                         \
        bb = fmaf(-aa, mI, mP);                                               \
    }

#define GF_STEP(r, S, SP1)                                                    \
  {                                                                           \
    const int gy = oy0 - 2 + (r);                                             \
    const bool ok = xok & ((unsigned)gy < (unsigned)H);                       \
    const float ix = ok ? fI[S].x : 0.f;                                      \
    const float iy = ok ? fI[S].y : 0.f;                                      \
    const float px = ok ? fP[S].x : 0.f;                                      \
    const float py = ok ? fP[S].y : 0.f;                                      \
    {   /* refill slot S with row r+3: clamped, UNCONDITIONAL */              \
        const int gn = gy + 3;                                                \
        const int gc = gn < 0 ? 0 : (gn > H - 1 ? H - 1 : gn);                \
        fI[S] = *(const float2*)(Ic0 + (size_t)gc * W);                       \
        fP[S] = *(const float2*)(Pc0 + (size_t)gc * W);                       \
    }                                                                         \
    const float iLy = __shfl(iy, lm1);                                        \
    const float pLy = __shfl(py, lm1);                                        \
    const float iRx = __shfl(ix, lp1);                                        \
    const float pRx = __shfl(px, lp1);                                        \
    const float cI = ix + iy, cP = px + py;                                   \
    hI0[S] = cI + iLy;  hI1[S] = cI + iRx;                                    \
    hP0[S] = cP + pLy;  hP1[S] = cP + pRx;                                    \
    const float cII = fmaf(ix, ix, iy * iy);                                  \
    const float cIP = fmaf(ix, px, iy * py);                                  \
    hII0[S] = fmaf(iLy, iLy, cII);  hII1[S] = fmaf(iRx, iRx, cII);            \
    hIP0[S] = fmaf(iLy, pLy, cIP);  hIP1[S] = fmaf(iRx, pRx, cIP);            \
    iC0[S] = ix; iC1[S] = iy;                                                 \
    const int ay = gy - 1;                                                    \
    const float cyA = 3.f - (float)(ay == 0) - (float)(ay == H - 1);          \
    const bool abok = xok & ((unsigned)ay < (unsigned)H);                     \
    float a0, b0, a1, b1;                                                     \
    GF_AB_COL(cx0, hI0[0] + hI0[1] + hI0[2], hP0[0] + hP0[1] + hP0[2],        \
              hII0[0] + hII0[1] + hII0[2], hIP0[0] + hIP0[1] + hIP0[2],       \
              a0, b0)                                                         \
    GF_AB_COL(cx1, hI1[0] + hI1[1] + hI1[2], hP1[0] + hP1[1] + hP1[2],        \
              hII1[0] + hII1[1] + hII1[2], hIP1[0] + hIP1[1] + hIP1[2],       \
              a1, b1)                                                         \
    a0 = abok ? a0 : 0.f;  b0 = abok ? b0 : 0.f;                              \
    a1 = abok ? a1 : 0.f;  b1 = abok ? b1 : 0.f;                              \
    const float aLy = __shfl(a1, lm1);                                        \
    const float bLy = __shfl(b1, lm1);                                        \
    const float aRx = __shfl(a0, lp1);                                        \
    const float bRx = __shfl(b0, lp1);                                        \
    const float cA = a0 + a1, cB = b0 + b1;                                   \
    hA0[S] = cA + aLy;  hA1[S] = cA + aRx;                                    \
    hB0[S] = cB + bLy;  hB1[S] = cB + bRx;                                    \
    if ((r) >= 4) {                                                           \
        const int oy = gy - 2;                                                \
        const float cyO = 3.f - (float)(oy == 0) - (float)(oy == H - 1);      \
        const float q0 = __builtin_amdgcn_rcpf(cx0 * cyO);                    \
        const float q1 = __builtin_amdgcn_rcpf(cx1 * cyO);                    \
        const float sA0 = hA0[0] + hA0[1] + hA0[2];                           \
        const float sB0 = hB0[0] + hB0[1] + hB0[2];                           \
        const float sA1 = hA1[0] + hA1[1] + hA1[2];                           \
        const float sB1 = hB1[0] + hB1[1] + hB1[2];                           \
        const float o0 = fmaf(sA0 * q0, iC0[SP1], sB0 * q0);                  \
        const float o1 = fmaf(sA1 * q1, iC1[SP1], sB1 * q1);                  \
        if (stok) *(float2*)(Ob + oy * W + c0) = make_float2(o0, o1);         \
    }                                                                         \
  }

__global__ __launch_bounds__(256, 4) void guide_filter_kernel(
    const float* __restrict__ I, const float* __restrict__ P,
    float* __restrict__ O)
{
    const int lane = threadIdx.x & 63;
    const int wid  = threadIdx.x >> 6;
    const int band = blockIdx.x;                  // 0..4
    const int rg   = blockIdx.y * 4 + wid;        // 0..15
    const size_t img_off = (size_t)blockIdx.z * (size_t)(W * H);
    const float* Ib = I + img_off;
    const float* Pb = P + img_off;
    float*       Ob = O + img_off;

    const int c0 = band * OUTW - 2 + 2 * lane;    // even -> float2 aligned
    const int c1 = c0 + 1;
    const int c0c = c0 < 0 ? 0 : (c0 > W - 2 ? W - 2 : c0);  // clamped, even
    const bool xok  = (unsigned)c0 < (unsigned)W;
    const bool stok = xok & (lane >= 1) & (lane <= 60);
    const float cx0 = 3.f - (float)(c0 == 0);     // c0 even, never W-1
    const float cx1 = 3.f - (float)(c1 == W - 1); // c1 odd, never 0
    const int oy0 = rg * RG_H;
    const int lm1 = lane - 1, lp1 = lane + 1;
    const float* Ic0 = Ib + c0c;
    const float* Pc0 = Pb + c0c;

    float hI0[3], hI1[3], hP0[3], hP1[3], hII0[3], hII1[3], hIP0[3], hIP1[3];
    float hA0[3], hA1[3], hB0[3], hB1[3], iC0[3], iC1[3];
    #pragma unroll
    for (int s = 0; s < 3; ++s) {
        hI0[s]=hI1[s]=hP0[s]=hP1[s]=hII0[s]=hII1[s]=hIP0[s]=hIP1[s]=0.f;
        hA0[s]=hA1[s]=hB0[s]=hB1[s]=iC0[s]=iC1[s]=0.f;
    }

    // Prologue: preload rows r=0,1,2 into prefetch slots (clamped).
    float2 fI[3], fP[3];
    #pragma unroll
    for (int s = 0; s < 3; ++s) {
        const int gn = oy0 - 2 + s;
        const int gc = gn < 0 ? 0 : (gn > H - 1 ? H - 1 : gn);
        fI[s] = *(const float2*)(Ic0 + (size_t)gc * W);
        fP[s] = *(const float2*)(Pc0 + (size_t)gc * W);
    }

    // 36 raw-row iterations = 12 groups of 3 (static ring slots, no tail).
    for (int g = 0; g < 12; ++g) {
        const int r = 3 * g;
        GF_STEP(r,     0, 1)
        GF_STEP(r + 1, 1, 2)
        GF_STEP(r + 2, 2, 0)
    }
}

extern "C" void kernel_launch(void* const* d_in, const int* in_sizes, int n_in,
                              void* d_out, int out_size, void* d_ws, size_t ws_size,
                              hipStream_t stream) {
    const float* I = (const float*)d_in[0];   // input
    const float* P = (const float*)d_in[1];   // guide
    float*       O = (float*)d_out;
    const int images = in_sizes[0] / (W * H); // B*C = 128
    dim3 grid(5, 4, images);                  // 5 bands x (4x4 waves) row-groups
    guide_filter_kernel<<<grid, dim3(256), 0, stream>>>(I, P, O);
}